// Round 17
// baseline (539.249 us; speedup 1.0000x reference)
//
#include <hip/hip_runtime.h>
#include <hip/hip_bf16.h>

#define NQ 20
#define NLAY 51            // N_LAYER+1
#define FEAT 128
#define BATCH 128
#define NN (BATCH * NQ * NLAY)   // 130560
#define NE 524288
#define NPAIR (BATCH * NQ * NQ)  // 51200
#define NB (NN / 256)            // 510
#define VOCAB 1021

typedef _Float16 half8 __attribute__((ext_vector_type(8)));
typedef float floatx4 __attribute__((ext_vector_type(4)));

__device__ __forceinline__ float lrelu(float v) { return v >= 0.f ? v : 0.01f * v; }

// ---------------- CSR build ----------------
__global__ void k_count(const int* __restrict__ dst, int* __restrict__ cnt) {
    int e = blockIdx.x * 256 + threadIdx.x;
    atomicAdd(&cnt[dst[e]], 1);
}

// offsets via block-scan + global cursor; also dinv, meta, S0 seed, idmap.
__global__ void k_offsets(const int* __restrict__ cnt, const int* __restrict__ x,
                          int* __restrict__ offs, float* __restrict__ dinv,
                          int4* __restrict__ meta, int* __restrict__ cursor,
                          int* __restrict__ flag1, int* __restrict__ idmap) {
    __shared__ int sm[256];
    __shared__ int sbase;
    int t = threadIdx.x, g = blockIdx.x * 256 + t;
    int v = cnt[g];
    sm[t] = v;
    __syncthreads();
    for (int s = 1; s < 256; s <<= 1) {
        int add = (t >= s) ? sm[t - s] : 0;
        __syncthreads();
        sm[t] += add;
        __syncthreads();
    }
    if (t == 255) sbase = atomicAdd(cursor, sm[255]);
    __syncthreads();
    int off = sbase + sm[t] - v;
    float di = rsqrtf((float)(v + 1));  // +1 self loop
    offs[g] = off;
    dinv[g] = di;
    meta[g] = make_int4(off, v, __float_as_int(di), x[g]);
    if (g % (NQ * NLAY) < NQ) flag1[g] = 1;      // S0 seed
    if (g < 1024) idmap[g] = min(g, VOCAB - 1);
}

// fill packed edges {src, norm_bits} and token edges {x[src], norm_bits};
// norm = dinv[src]*dinv[dst]. Also mark flag1[src] for S0 dsts.
__global__ void k_fill(const int* __restrict__ src, const int* __restrict__ dst,
                       const int* __restrict__ offs, int* __restrict__ fill,
                       const float* __restrict__ dinv, const int* __restrict__ x,
                       int2* __restrict__ csre, int2* __restrict__ csre0,
                       int* __restrict__ flag1) {
    int e = blockIdx.x * 256 + threadIdx.x;
    int d = dst[e];
    int s = src[e];
    int pos = offs[d] + atomicAdd(&fill[d], 1);
    int wb = __float_as_int(dinv[s] * dinv[d]);
    csre[pos] = make_int2(s, wb);
    csre0[pos] = make_int2(x[s], wb);
    if (d % (NQ * NLAY) < NQ) flag1[s] = 1;      // src feeds an S0 node
}

// generic cone pass: emit listO from flagI (cursor-packed dense prefix) and, if flagO,
// mark flagO = flagI-members ∪ their in-neighbors
__global__ void k_s1pass(const int* __restrict__ flagI, const int4* __restrict__ meta,
                         const int2* __restrict__ csre, int* __restrict__ cur,
                         int* __restrict__ listO, int* __restrict__ flagO) {
    __shared__ int sm[256];
    __shared__ int sbase;
    int t = threadIdx.x, g = blockIdx.x * 256 + t;
    int v = flagI[g];
    sm[t] = v;
    __syncthreads();
    for (int s = 1; s < 256; s <<= 1) {
        int add = (t >= s) ? sm[t - s] : 0;
        __syncthreads();
        sm[t] += add;
        __syncthreads();
    }
    if (t == 255) sbase = atomicAdd(cur, sm[255]);
    __syncthreads();
    if (v) {
        listO[sbase + sm[t] - 1] = g;
        if (flagO) {
            flagO[g] = 1;
            int4 m = meta[g];
            for (int e = 0; e < m.y; e++) flagO[csre[m.x + e].x] = 1;   // benign races
        }
    }
}

// emit list from flag (cursor-packed)
__global__ void k_emit2(const int* __restrict__ flag, int* __restrict__ cur,
                        int* __restrict__ list) {
    __shared__ int sm[256];
    __shared__ int sbase;
    int t = threadIdx.x, g = blockIdx.x * 256 + t;
    int v = flag[g];
    sm[t] = v;
    __syncthreads();
    for (int s = 1; s < 256; s <<= 1) {
        int add = (t >= s) ? sm[t - s] : 0;
        __syncthreads();
        sm[t] += add;
        __syncthreads();
    }
    if (t == 255) sbase = atomicAdd(cur, sm[255]);
    __syncthreads();
    if (v) list[sbase + sm[t] - 1] = g;
}

// ---------------- weight transpose + fp16 hi/lo split, PACKED MFMA-fragment layout -------
#define OFF_GCN 0                 // 5 x K=128 N=128
#define OFF_P0  81920             // combined mw0: K=128 N=512
#define OFF_M1  147456            // mw1: K=256 N=128
#define OFF_M2  180224            // mw2: K=128 N=128
#define OFF_M3  196608            // mw3: K=128 N=64
#define OFF_M4  204800            // mw4: K=64  N=64
#define TS_TOTAL 208896

__global__ void k_tsplit_all(const float* __restrict__ gw, const float* __restrict__ mw0,
                             const float* __restrict__ mw1, const float* __restrict__ mw2,
                             const float* __restrict__ mw3, const float* __restrict__ mw4,
                             _Float16* __restrict__ hi, _Float16* __restrict__ lo) {
    int idx = blockIdx.x * 256 + threadIdx.x;
    const float* src;
    int K, N, rel;
    bool p0 = false;
    if (idx < OFF_P0) {
        int L = (idx - OFF_GCN) >> 14; rel = (idx - OFF_GCN) & 16383;
        src = gw + L * 16384; K = 128; N = 128;
    } else if (idx < OFF_M1) {
        rel = idx - OFF_P0; src = mw0; K = 128; N = 512; p0 = true;
    } else if (idx < OFF_M2) {
        rel = idx - OFF_M1;  src = mw1; K = 256; N = 128;
    } else if (idx < OFF_M3) {
        rel = idx - OFF_M2;  src = mw2; K = 128; N = 128;
    } else if (idx < OFF_M4) {
        rel = idx - OFF_M3;  src = mw3; K = 128; N = 64;
    } else {
        rel = idx - OFF_M4;  src = mw4; K = 64;  N = 64;
    }
    int kblks = K >> 5;
    int j = rel & 7;
    int lane = (rel >> 3) & 63;
    int t2 = rel >> 9;
    int kblk = t2 % kblks;
    int ntile = t2 / kblks;
    int col = ntile * 16 + (lane & 15);
    int k = kblk * 32 + ((lane >> 4) << 3) + j;
    float f;
    if (p0) {
        f = (col < 256) ? src[k * 256 + col] : src[(k + 128) * 256 + (col - 256)];
    } else {
        f = src[k * N + col];
    }
    _Float16 h = (_Float16)f;
    hi[idx] = h;
    lo[idx] = (_Float16)(f - (float)h);
}

// ---------------- split-fp16 MFMA GEMM, BM=64, LDS-staged A ----------------
// B pre-packed in fragment order (hi/lo). 3-product Markidis split, fp32 accumulate.
// Non-FUSEA paths stage the 64-row A-tile through LDS with coalesced 512B row reads
// (XOR-swizzled float4: fragment ds_reads are 2-way bank aliased = free).
// GATHA: rows via gmap. LISTM: sentinel-padded dense-prefix list (block early exit).
template <int NT_N, bool LEAKY, bool BIAS, bool P0SPLIT, bool FUSEA, bool GATHA, bool LISTM>
__launch_bounds__(256, 2)
__global__ void hgemm(const float* __restrict__ A,
                      const float* __restrict__ FA, const float* __restrict__ FB,
                      const _Float16* __restrict__ Bh, const _Float16* __restrict__ Bl,
                      const float* __restrict__ bias,
                      float* __restrict__ C, float* __restrict__ C2,
                      int N, int K, const int* __restrict__ gmap,
                      const int* __restrict__ listm) {
    if (LISTM) {
        if ((unsigned)listm[blockIdx.x * 64] >= (unsigned)NN) return;  // all-sentinel block
    }
    __shared__ float4 sA[64][32];   // 32 KB; col swizzle c4 ^ (row & 7)
    const int KB = K >> 5;
    const int tid = threadIdx.x;
    const int lane = tid & 63;
    const int wid = tid >> 6;
    const int lm = lane & 15, lq = lane >> 4;
    const int m0 = blockIdx.x * 64;
    const int n0t = blockIdx.y * NT_N;

    const float* arow = nullptr;
    const float* brow = nullptr;
    if (FUSEA) {
        int row = m0 + wid * 16 + lm;
        int b = row / (NQ * NQ);
        int rr = row - b * (NQ * NQ);
        int i = rr / NQ;
        int j = rr - i * NQ;
        arow = FA + (size_t)(b * NQ + i) * 256;
        brow = FB + (size_t)(b * NQ + j) * 256;
    } else {
        // ---- stage A tile: 64 rows x K floats, coalesced per row ----
        int kq = K >> 2;   // float4s per row (16 or 32)
        for (int idx = tid; idx < 64 * kq; idx += 256) {
            int row = idx / kq;
            int c4 = idx - row * kq;
            int grow = m0 + row;
            const float* ap;
            if (GATHA) {
                ap = A + (size_t)gmap[grow] * K;
            } else if (LISTM) {
                int lr = listm[grow];
                lr = ((unsigned)lr < (unsigned)NN) ? lr : 0;
                ap = A + (size_t)lr * K;
            } else {
                ap = A + (size_t)grow * K;
            }
            sA[row][c4 ^ (row & 7)] = ((const float4*)ap)[c4];
        }
        __syncthreads();
    }

    floatx4 acc[NT_N];
#pragma unroll
    for (int nt = 0; nt < NT_N; nt++) acc[nt] = (floatx4)0.f;

    const int lrow = wid * 16 + lm;
    for (int kb = 0; kb < KB; kb++) {
        half8 ahi, alo;
        {
            floatx4 av0, av1;
            if (FUSEA) {
                const int k0 = kb * 32 + lq * 8;
                floatx4 fa0 = *(const floatx4*)(arow + k0);
                floatx4 fa1 = *(const floatx4*)(arow + k0 + 4);
                floatx4 fb0 = *(const floatx4*)(brow + k0);
                floatx4 fb1 = *(const floatx4*)(brow + k0 + 4);
#pragma unroll
                for (int q = 0; q < 4; q++) {
                    av0[q] = lrelu(fa0[q] + fb0[q]);
                    av1[q] = lrelu(fa1[q] + fb1[q]);
                }
            } else {
                int c4 = kb * 8 + lq * 2;
                float4 t0 = sA[lrow][c4 ^ (lrow & 7)];
                float4 t1 = sA[lrow][(c4 + 1) ^ (lrow & 7)];
                av0[0] = t0.x; av0[1] = t0.y; av0[2] = t0.z; av0[3] = t0.w;
                av1[0] = t1.x; av1[1] = t1.y; av1[2] = t1.z; av1[3] = t1.w;
            }
#pragma unroll
            for (int q = 0; q < 4; q++) {
                _Float16 h0 = (_Float16)av0[q];
                ahi[q] = h0;
                alo[q] = (_Float16)(av0[q] - (float)h0);
                _Float16 h1 = (_Float16)av1[q];
                ahi[4 + q] = h1;
                alo[4 + q] = (_Float16)(av1[q] - (float)h1);
            }
        }
#pragma unroll
        for (int nt = 0; nt < NT_N; nt++) {
            size_t boff = (((size_t)(n0t + nt) * KB + kb) * 64 + lane) * 8;
            half8 bhi = *(const half8*)(Bh + boff);
            half8 blo = *(const half8*)(Bl + boff);
            acc[nt] = __builtin_amdgcn_mfma_f32_16x16x32_f16(ahi, bhi, acc[nt], 0, 0, 0);
            acc[nt] = __builtin_amdgcn_mfma_f32_16x16x32_f16(ahi, blo, acc[nt], 0, 0, 0);
            acc[nt] = __builtin_amdgcn_mfma_f32_16x16x32_f16(alo, bhi, acc[nt], 0, 0, 0);
        }
    }

    // store-row mapping (C/D layout: col=lane&15, row=(lane>>4)*4+reg)
    int strow[4];
    bool svalid[4];
#pragma unroll
    for (int r = 0; r < 4; r++) {
        int mlog = m0 + wid * 16 + lq * 4 + r;
        if (LISTM) {
            int sr = listm[mlog];
            svalid[r] = (unsigned)sr < (unsigned)NN;
            strow[r] = svalid[r] ? sr : 0;
        } else {
            svalid[r] = true;
            strow[r] = mlog;
        }
    }

#pragma unroll
    for (int nt = 0; nt < NT_N; nt++) {
        int col = (n0t + nt) * 16 + lm;
        float bv = (BIAS || P0SPLIT) ? bias[col < 256 ? col : 0] : 0.f;
#pragma unroll
        for (int r = 0; r < 4; r++) {
            if (!svalid[r]) continue;
            int row = strow[r];
            float val = acc[nt][r];
            if (P0SPLIT) {
                if (col < 256) C[(size_t)row * 256 + col] = val + bv;
                else C2[(size_t)row * 256 + col - 256] = val;
            } else {
                if (BIAS) val += bv;
                if (LEAKY) val = lrelu(val);
                C[(size_t)row * N + col] = val;
            }
        }
    }
}

// ---------------- layer-0 aggregation from the L2-resident token table ----------------
__global__ void k_agg0(const float* __restrict__ embW, const float* __restrict__ emb,
                       float* __restrict__ h,
                       const int4* __restrict__ meta, const int2* __restrict__ csre0,
                       const float* __restrict__ bias) {
    int tid = threadIdx.x;
    int sl = tid & 31;
    int p = blockIdx.x * 8 + (tid >> 5);
    int n0 = p * 2, n1 = n0 + 1;
    int4 m0 = meta[n0], m1 = meta[n1];
    float di0 = __int_as_float(m0.z), di1 = __int_as_float(m1.z);
    int off0 = m0.x, deg0 = m0.y;
    int off1 = m1.x, deg1 = m1.y;
    float4 v0 = ((const float4*)(embW + (size_t)m0.w * FEAT))[sl];
    float4 v1 = ((const float4*)(embW + (size_t)m1.w * FEAT))[sl];
    float4 ho0 = ((const float4*)(emb + (size_t)m0.w * FEAT))[sl];
    float4 ho1 = ((const float4*)(emb + (size_t)m1.w * FEAT))[sl];
    float s20 = di0 * di0, s21 = di1 * di1;
    float a0x = v0.x * s20, a0y = v0.y * s20, a0z = v0.z * s20, a0w = v0.w * s20;
    float a1x = v1.x * s21, a1y = v1.y * s21, a1z = v1.z * s21, a1w = v1.w * s21;
    int d0c = max(deg0 - 1, 0), d1c = max(deg1 - 1, 0);
    int dm = max(deg0, deg1);
    for (int e = 0; e < dm; e += 4) {
        int2 e00 = csre0[off0 + min(e,     d0c)];
        int2 e01 = csre0[off0 + min(e + 1, d0c)];
        int2 e02 = csre0[off0 + min(e + 2, d0c)];
        int2 e03 = csre0[off0 + min(e + 3, d0c)];
        int2 e10 = csre0[off1 + min(e,     d1c)];
        int2 e11 = csre0[off1 + min(e + 1, d1c)];
        int2 e12 = csre0[off1 + min(e + 2, d1c)];
        int2 e13 = csre0[off1 + min(e + 3, d1c)];
        float4 u00 = ((const float4*)(embW + (size_t)e00.x * FEAT))[sl];
        float4 u01 = ((const float4*)(embW + (size_t)e01.x * FEAT))[sl];
        float4 u02 = ((const float4*)(embW + (size_t)e02.x * FEAT))[sl];
        float4 u03 = ((const float4*)(embW + (size_t)e03.x * FEAT))[sl];
        float4 u10 = ((const float4*)(embW + (size_t)e10.x * FEAT))[sl];
        float4 u11 = ((const float4*)(embW + (size_t)e11.x * FEAT))[sl];
        float4 u12 = ((const float4*)(embW + (size_t)e12.x * FEAT))[sl];
        float4 u13 = ((const float4*)(embW + (size_t)e13.x * FEAT))[sl];
        float w00 = (e     < deg0) ? __int_as_float(e00.y) : 0.f;
        float w01 = (e + 1 < deg0) ? __int_as_float(e01.y) : 0.f;
        float w02 = (e + 2 < deg0) ? __int_as_float(e02.y) : 0.f;
        float w03 = (e + 3 < deg0) ? __int_as_float(e03.y) : 0.f;
        float w10 = (e     < deg1) ? __int_as_float(e10.y) : 0.f;
        float w11 = (e + 1 < deg1) ? __int_as_float(e11.y) : 0.f;
        float w12 = (e + 2 < deg1) ? __int_as_float(e12.y) : 0.f;
        float w13 = (e + 3 < deg1) ? __int_as_float(e13.y) : 0.f;
        a0x += u00.x * w00 + u01.x * w01 + u02.x * w02 + u03.x * w03;
        a0y += u00.y * w00 + u01.y * w01 + u02.y * w02 + u03.y * w03;
        a0z += u00.z * w00 + u01.z * w01 + u02.z * w02 + u03.z * w03;
        a0w += u00.w * w00 + u01.w * w01 + u02.w * w02 + u03.w * w03;
        a1x += u10.x * w10 + u11.x * w11 + u12.x * w12 + u13.x * w13;
        a1y += u10.y * w10 + u11.y * w11 + u12.y * w12 + u13.y * w13;
        a1z += u10.z * w10 + u11.z * w11 + u12.z * w12 + u13.z * w13;
        a1w += u10.w * w10 + u11.w * w11 + u12.w * w12 + u13.w * w13;
    }
    float4 bv = ((const float4*)bias)[sl];
    float4 r0, r1;
    r0.x = lrelu(a0x + bv.x) + ho0.x;
    r0.y = lrelu(a0y + bv.y) + ho0.y;
    r0.z = lrelu(a0z + bv.z) + ho0.z;
    r0.w = lrelu(a0w + bv.w) + ho0.w;
    r1.x = lrelu(a1x + bv.x) + ho1.x;
    r1.y = lrelu(a1y + bv.y) + ho1.y;
    r1.z = lrelu(a1z + bv.z) + ho1.z;
    r1.w = lrelu(a1w + bv.w) + ho1.w;
    ((float4*)(h + (size_t)n0 * FEAT))[sl] = r0;
    ((float4*)(h + (size_t)n1 * FEAT))[sl] = r1;
}

// ---------------- GCN aggregation + bias + leaky + residual, h IN PLACE ----------------
// Sentinel-padded dense-prefix list; block early exit; clamp; store suppress.
__global__ void k_agg(const float* __restrict__ hw, float* __restrict__ h,
                      const int4* __restrict__ meta, const int2* __restrict__ csre,
                      const int* __restrict__ list,
                      const float* __restrict__ bias) {
    if ((unsigned)list[blockIdx.x * 16] >= (unsigned)NN) return;  // all-sentinel block
    int tid = threadIdx.x;
    int sl = tid & 31;
    int p = blockIdx.x * 8 + (tid >> 5);
    int n0 = list[p * 2];
    int n1 = list[p * 2 + 1];
    bool val0 = (unsigned)n0 < (unsigned)NN;
    bool val1 = (unsigned)n1 < (unsigned)NN;
    n0 = val0 ? n0 : 0;
    n1 = val1 ? n1 : 0;
    int4 m0 = meta[n0], m1 = meta[n1];
    float di0 = __int_as_float(m0.z), di1 = __int_as_float(m1.z);
    int off0 = m0.x, deg0 = val0 ? m0.y : 0;
    int off1 = m1.x, deg1 = val1 ? m1.y : 0;
    float4 v0 = ((const float4*)(hw + (size_t)n0 * FEAT))[sl];
    float4 v1 = ((const float4*)(hw + (size_t)n1 * FEAT))[sl];
    float4 ho0 = ((const float4*)(h + (size_t)n0 * FEAT))[sl];
    float4 ho1 = ((const float4*)(h + (size_t)n1 * FEAT))[sl];
    float s20 = di0 * di0, s21 = di1 * di1;
    float a0x = v0.x * s20, a0y = v0.y * s20, a0z = v0.z * s20, a0w = v0.w * s20;
    float a1x = v1.x * s21, a1y = v1.y * s21, a1z = v1.z * s21, a1w = v1.w * s21;
    int d0c = max(deg0 - 1, 0), d1c = max(deg1 - 1, 0);
    int dm = max(deg0, deg1);
    for (int e = 0; e < dm; e += 6) {
        int2 e00 = csre[off0 + min(e,     d0c)];
        int2 e01 = csre[off0 + min(e + 1, d0c)];
        int2 e02 = csre[off0 + min(e + 2, d0c)];
        int2 e03 = csre[off0 + min(e + 3, d0c)];
        int2 e04 = csre[off0 + min(e + 4, d0c)];
        int2 e05 = csre[off0 + min(e + 5, d0c)];
        int2 e10 = csre[off1 + min(e,     d1c)];
        int2 e11 = csre[off1 + min(e + 1, d1c)];
        int2 e12 = csre[off1 + min(e + 2, d1c)];
        int2 e13 = csre[off1 + min(e + 3, d1c)];
        int2 e14 = csre[off1 + min(e + 4, d1c)];
        int2 e15 = csre[off1 + min(e + 5, d1c)];
        float4 u00 = ((const float4*)(hw + (size_t)e00.x * FEAT))[sl];
        float4 u01 = ((const float4*)(hw + (size_t)e01.x * FEAT))[sl];
        float4 u02 = ((const float4*)(hw + (size_t)e02.x * FEAT))[sl];
        float4 u03 = ((const float4*)(hw + (size_t)e03.x * FEAT))[sl];
        float4 u04 = ((const float4*)(hw + (size_t)e04.x * FEAT))[sl];
        float4 u05 = ((const float4*)(hw + (size_t)e05.x * FEAT))[sl];
        float4 u10 = ((const float4*)(hw + (size_t)e10.x * FEAT))[sl];
        float4 u11 = ((const float4*)(hw + (size_t)e11.x * FEAT))[sl];
        float4 u12 = ((const float4*)(hw + (size_t)e12.x * FEAT))[sl];
        float4 u13 = ((const float4*)(hw + (size_t)e13.x * FEAT))[sl];
        float4 u14 = ((const float4*)(hw + (size_t)e14.x * FEAT))[sl];
        float4 u15 = ((const float4*)(hw + (size_t)e15.x * FEAT))[sl];
        float w00 = (e     < deg0) ? __int_as_float(e00.y) : 0.f;
        float w01 = (e + 1 < deg0) ? __int_as_float(e01.y) : 0.f;
        float w02 = (e + 2 < deg0) ? __int_as_float(e02.y) : 0.f;
        float w03 = (e + 3 < deg0) ? __int_as_float(e03.y) : 0.f;
        float w04 = (e + 4 < deg0) ? __int_as_float(e04.y) : 0.f;
        float w05 = (e + 5 < deg0) ? __int_as_float(e05.y) : 0.f;
        float w10 = (e     < deg1) ? __int_as_float(e10.y) : 0.f;
        float w11 = (e + 1 < deg1) ? __int_as_float(e11.y) : 0.f;
        float w12 = (e + 2 < deg1) ? __int_as_float(e12.y) : 0.f;
        float w13 = (e + 3 < deg1) ? __int_as_float(e13.y) : 0.f;
        float w14 = (e + 4 < deg1) ? __int_as_float(e14.y) : 0.f;
        float w15 = (e + 5 < deg1) ? __int_as_float(e15.y) : 0.f;
        a0x += u00.x * w00 + u01.x * w01 + u02.x * w02 + u03.x * w03 + u04.x * w04 + u05.x * w05;
        a0y += u00.y * w00 + u01.y * w01 + u02.y * w02 + u03.y * w03 + u04.y * w04 + u05.y * w05;
        a0z += u00.z * w00 + u01.z * w01 + u02.z * w02 + u03.z * w03 + u04.z * w04 + u05.z * w05;
        a0w += u00.w * w00 + u01.w * w01 + u02.w * w02 + u03.w * w03 + u04.w * w04 + u05.w * w05;
        a1x += u10.x * w10 + u11.x * w11 + u12.x * w12 + u13.x * w13 + u14.x * w14 + u15.x * w15;
        a1y += u10.y * w10 + u11.y * w11 + u12.y * w12 + u13.y * w13 + u14.y * w14 + u15.y * w15;
        a1z += u10.z * w10 + u11.z * w11 + u12.z * w12 + u13.z * w13 + u14.z * w14 + u15.z * w15;
        a1w += u10.w * w10 + u11.w * w11 + u12.w * w12 + u13.w * w13 + u14.w * w14 + u15.w * w15;
    }
    float4 bv = ((const float4*)bias)[sl];
    float4 r0, r1;
    r0.x = lrelu(a0x + bv.x) + ho0.x;
    r0.y = lrelu(a0y + bv.y) + ho0.y;
    r0.z = lrelu(a0z + bv.z) + ho0.z;
    r0.w = lrelu(a0w + bv.w) + ho0.w;
    r1.x = lrelu(a1x + bv.x) + ho1.x;
    r1.y = lrelu(a1y + bv.y) + ho1.y;
    r1.z = lrelu(a1z + bv.z) + ho1.z;
    r1.w = lrelu(a1w + bv.w) + ho1.w;
    if (val0) ((float4*)(h + (size_t)n0 * FEAT))[sl] = r0;
    if (val1) ((float4*)(h + (size_t)n1 * FEAT))[sl] = r1;
}

// ---------------- selective final agg (layer 4): S0 rows only -> hq, no leaky ----------------
__global__ void k_aggq(const float* __restrict__ hw, const float* __restrict__ h,
                       const int4* __restrict__ meta, const int2* __restrict__ csre,
                       const float* __restrict__ gbias, float* __restrict__ hq) {
    int tid = threadIdx.x;
    int sl = tid & 31;
    int q = blockIdx.x * 8 + (tid >> 5);   // 0..2559
    int b = q / NQ, i = q - b * NQ;
    int node = b * (NQ * NLAY) + i;
    int4 m = meta[node];
    float di = __int_as_float(m.z);
    int off = m.x, deg = m.y;
    float s2 = di * di;
    float4 v = ((const float4*)(hw + (size_t)node * FEAT))[sl];
    float ax = v.x * s2, ay = v.y * s2, az = v.z * s2, aw = v.w * s2;
    int dc = max(deg - 1, 0);
    for (int e = 0; e < deg; e += 4) {
        int2 e0 = csre[off + min(e,     dc)];
        int2 e1 = csre[off + min(e + 1, dc)];
        int2 e2 = csre[off + min(e + 2, dc)];
        int2 e3 = csre[off + min(e + 3, dc)];
        float4 u0 = ((const float4*)(hw + (size_t)e0.x * FEAT))[sl];
        float4 u1 = ((const float4*)(hw + (size_t)e1.x * FEAT))[sl];
        float4 u2 = ((const float4*)(hw + (size_t)e2.x * FEAT))[sl];
        float4 u3 = ((const float4*)(hw + (size_t)e3.x * FEAT))[sl];
        float w0 = (e     < deg) ? __int_as_float(e0.y) : 0.f;
        float w1 = (e + 1 < deg) ? __int_as_float(e1.y) : 0.f;
        float w2 = (e + 2 < deg) ? __int_as_float(e2.y) : 0.f;
        float w3 = (e + 3 < deg) ? __int_as_float(e3.y) : 0.f;
        ax += u0.x * w0 + u1.x * w1 + u2.x * w2 + u3.x * w3;
        ay += u0.y * w0 + u1.y * w1 + u2.y * w2 + u3.y * w3;
        az += u0.z * w0 + u1.z * w1 + u2.z * w2 + u3.z * w3;
        aw += u0.w * w0 + u1.w * w1 + u2.w * w2 + u3.w * w3;
    }
    float4 bv = ((const float4*)gbias)[sl];
    float4 ho = ((const float4*)(h + (size_t)node * FEAT))[sl];
    ((float4*)(hq + (size_t)q * FEAT))[sl] =
        make_float4(ax + bv.x + ho.x, ay + bv.y + ho.y, az + bv.z + ho.z, aw + bv.w + ho.w);
}

// ---------------- last layer + symmetrize, one block per batch ----------------
__global__ void k_lastsym(const float* __restrict__ X4, const float* __restrict__ mw5,
                          const float* __restrict__ mb5, float* __restrict__ out) {
    __shared__ float w[64];
    __shared__ float sm[NQ * NQ];
    int t = threadIdx.x;
    if (t < 64) w[t] = mw5[t];
    __syncthreads();
    int b = blockIdx.x;
    for (int p = t; p < NQ * NQ; p += 256) {
        const float4* row = (const float4*)(X4 + (size_t)(b * NQ * NQ + p) * 64);
        float s = 0.f;
#pragma unroll
        for (int k4 = 0; k4 < 16; k4++) {
            float4 v = row[k4];
            s += v.x * w[k4 * 4] + v.y * w[k4 * 4 + 1] + v.z * w[k4 * 4 + 2] + v.w * w[k4 * 4 + 3];
        }
        sm[p] = s + mb5[0];
    }
    __syncthreads();
    for (int r = t; r < NQ * NQ; r += 256) {
        int i = r / NQ, j = r % NQ;
        out[(size_t)b * NQ * NQ + r] = 0.5f * (sm[r] + sm[j * NQ + i]);
    }
}

extern "C" void kernel_launch(void* const* d_in, const int* in_sizes, int n_in,
                              void* d_out, int out_size, void* d_ws, size_t ws_size,
                              hipStream_t stream) {
    const int* x = (const int*)d_in[0];
    const int* ei = (const int*)d_in[1];
    const int* e_src = ei;
    const int* e_dst = ei + NE;
    const float* emb = (const float*)d_in[2];
    const float* gw = (const float*)d_in[3];   // [5,128,128]
    const float* gb = (const float*)d_in[4];   // [5,128]
    const float* mw0 = (const float*)d_in[5];
    const float* mb0 = (const float*)d_in[6];
    const float* mw1 = (const float*)d_in[7];
    const float* mb1 = (const float*)d_in[8];
    const float* mw2 = (const float*)d_in[9];
    const float* mb2 = (const float*)d_in[10];
    const float* mw3 = (const float*)d_in[11];
    const float* mb3 = (const float*)d_in[12];
    const float* mw4 = (const float*)d_in[13];
    const float* mb4 = (const float*)d_in[14];
    const float* mw5 = (const float*)d_in[15];
    const float* mb5 = (const float*)d_in[16];
    float* out = (float*)d_out;

    float* wsf = (float*)d_ws;
    size_t o = 0;
    const size_t HSZ = (size_t)NN * FEAT;             // 16,711,680
    float* h  = wsf + o; o += HSZ;    // single in-place h buffer
    float* hw = wsf + o; o += HSZ;
    // zero-memset region: cnt, fill, flag1, flag2, flag3, cursors (contiguous)
    int* cnt   = (int*)(wsf + o); o += NN;
    int* fill  = (int*)(wsf + o); o += NN;
    int* flag1 = (int*)(wsf + o); o += NN;
    int* flag2 = (int*)(wsf + o); o += NN;
    int* flag3 = (int*)(wsf + o); o += NN;
    int* curs  = (int*)(wsf + o); o += 16;   // [0]=offs [1]=list1 [2]=list2 [3]=list3
    // 0xFF-memset region: list1, list2, list3 (contiguous, sentinel -1)
    int* list1 = (int*)(wsf + o); o += NN;
    int* list2 = (int*)(wsf + o); o += NN;
    int* list3 = (int*)(wsf + o); o += NN;
    int* offs = (int*)(wsf + o); o += NN;
    float* dinv = wsf + o; o += NN;
    int4* meta = (int4*)(wsf + o); o += 4 * (size_t)NN;
    int2* csre  = (int2*)(wsf + o); o += 2 * (size_t)(NE + 8);  // +8 slop for deg-0 clamp
    int2* csre0 = (int2*)(wsf + o); o += 2 * (size_t)(NE + 8);  // token edges
    int* idmap = (int*)(wsf + o); o += 1024;
    float* embW = wsf + o; o += (size_t)1024 * FEAT;          // emb@W0 table
    float* hq = wsf + o; o += (size_t)BATCH * NQ * FEAT;      // 327,680
    float* Abuf = wsf + o; o += (size_t)BATCH * NQ * 256;     // 655,360
    float* Bbuf = wsf + o; o += (size_t)BATCH * NQ * 256;     // 655,360
    _Float16* bt_hi = (_Float16*)(wsf + o); o += (TS_TOTAL + 2) / 2;
    _Float16* bt_lo = (_Float16*)(wsf + o); o += (TS_TOTAL + 2) / 2;
    // pair-phase aliases (hw, h dead after aggq)
    float* X1 = hw;                         // 51200*128
    float* X2 = hw + (size_t)NPAIR * 128;   // 51200*128
    float* X3 = h;                          // 51200*64
    float* X4 = h + (size_t)NPAIR * 64;     // 51200*64

    // --- weight transpose+split+pack ---
    k_tsplit_all<<<TS_TOTAL / 256, 256, 0, stream>>>(gw, mw0, mw1, mw2, mw3, mw4, bt_hi, bt_lo);

    // --- CSR build + cone lists S1/S2/S3 ---
    hipMemsetAsync(cnt, 0, (5 * NN + 16) * sizeof(int), stream); // cnt+fill+flags+cursors
    hipMemsetAsync(list1, 0xFF, 3 * NN * sizeof(int), stream);   // list sentinels (-1)
    hipMemsetAsync(csre + NE, 0, 8 * sizeof(int2), stream);      // slop
    hipMemsetAsync(csre0 + NE, 0, 8 * sizeof(int2), stream);     // slop
    k_count<<<NE / 256, 256, 0, stream>>>(e_dst, cnt);
    k_offsets<<<NB, 256, 0, stream>>>(cnt, x, offs, dinv, meta, curs + 0, flag1, idmap);
    k_fill<<<NE / 256, 256, 0, stream>>>(e_src, e_dst, offs, fill, dinv, x, csre, csre0, flag1);
    k_s1pass<<<NB, 256, 0, stream>>>(flag1, meta, csre, curs + 1, list1, flag2);  // S1 + mark S2
    k_s1pass<<<NB, 256, 0, stream>>>(flag2, meta, csre, curs + 2, list2, flag3);  // S2 + mark S3
    k_emit2<<<NB, 256, 0, stream>>>(flag3, curs + 3, list3);                      // S3

    // --- layer 0 via token table: embW = emb@W0 (1021 rows, clamped id map) ---
    hgemm<8, false, false, false, false, true, false><<<dim3(16, 1), 256, 0, stream>>>(
        emb, nullptr, nullptr, bt_hi + OFF_GCN, bt_lo + OFF_GCN,
        nullptr, embW, nullptr, FEAT, FEAT, idmap, nullptr);
    k_agg0<<<NN / 16, 256, 0, stream>>>(embW, emb, h, meta, csre0, gb + 0 * FEAT);

    // --- layer 1: full gemm + agg@S3 ---
    hgemm<8, false, false, false, false, false, false><<<dim3(NN / 64, 1), 256, 0, stream>>>(
        h, nullptr, nullptr, bt_hi + OFF_GCN + 1 * 16384, bt_lo + OFF_GCN + 1 * 16384,
        nullptr, hw, nullptr, FEAT, FEAT, nullptr, nullptr);
    k_agg<<<NN / 16, 256, 0, stream>>>(hw, h, meta, csre, list3, gb + 1 * FEAT);

    // --- layer 2: gemm@S3 + agg@S2 ---
    hgemm<8, false, false, false, false, false, true><<<dim3(NN / 64, 1), 256, 0, stream>>>(
        h, nullptr, nullptr, bt_hi + OFF_GCN + 2 * 16384, bt_lo + OFF_GCN + 2 * 16384,
        nullptr, hw, nullptr, FEAT, FEAT, nullptr, list3);
    k_agg<<<NN / 16, 256, 0, stream>>>(hw, h, meta, csre, list2, gb + 2 * FEAT);

    // --- layer 3: gemm@S2 + agg@S1 ---
    hgemm<8, false, false, false, false, false, true><<<dim3(NN / 64, 1), 256, 0, stream>>>(
        h, nullptr, nullptr, bt_hi + OFF_GCN + 3 * 16384, bt_lo + OFF_GCN + 3 * 16384,
        nullptr, hw, nullptr, FEAT, FEAT, nullptr, list2);
    k_agg<<<NN / 16, 256, 0, stream>>>(hw, h, meta, csre, list1, gb + 3 * FEAT);

    // --- layer 4: gemm@S1 + selective agg@S0 -> hq ---
    hgemm<8, false, false, false, false, false, true><<<dim3(NN / 64, 1), 256, 0, stream>>>(
        h, nullptr, nullptr, bt_hi + OFF_GCN + 4 * 16384, bt_lo + OFF_GCN + 4 * 16384,
        nullptr, hw, nullptr, FEAT, FEAT, nullptr, list1);
    k_aggq<<<(BATCH * NQ) / 8, 256, 0, stream>>>(hw, h, meta, csre,
                                                 gb + 4 * (size_t)FEAT, hq);

    // --- pair MLP ---
    hgemm<8, false, false, true, false, false, false><<<dim3(40, 4), 256, 0, stream>>>(
        hq, nullptr, nullptr, bt_hi + OFF_P0, bt_lo + OFF_P0, mb0, Abuf, Bbuf, 512, 128,
        nullptr, nullptr);
    hgemm<8, true, true, false, true, false, false><<<dim3(NPAIR / 64, 1), 256, 0, stream>>>(
        nullptr, Abuf, Bbuf, bt_hi + OFF_M1, bt_lo + OFF_M1, mb1, X1, nullptr, 128, 256,
        nullptr, nullptr);
    hgemm<8, true, true, false, false, false, false><<<dim3(NPAIR / 64, 1), 256, 0, stream>>>(
        X1, nullptr, nullptr, bt_hi + OFF_M2, bt_lo + OFF_M2, mb2, X2, nullptr, 128, 128,
        nullptr, nullptr);
    hgemm<4, true, true, false, false, false, false><<<dim3(NPAIR / 64, 1), 256, 0, stream>>>(
        X2, nullptr, nullptr, bt_hi + OFF_M3, bt_lo + OFF_M3, mb3, X3, nullptr, 64, 128,
        nullptr, nullptr);
    hgemm<4, true, true, false, false, false, false><<<dim3(NPAIR / 64, 1), 256, 0, stream>>>(
        X3, nullptr, nullptr, bt_hi + OFF_M4, bt_lo + OFF_M4, mb4, X4, nullptr, 64, 64,
        nullptr, nullptr);
    k_lastsym<<<BATCH, 256, 0, stream>>>(X4, mw5, mb5, out);
}

// Round 18
// 533.877 us; speedup vs baseline: 1.0101x; 1.0101x over previous
//
#include <hip/hip_runtime.h>
#include <hip/hip_bf16.h>

#define NQ 20
#define NLAY 51            // N_LAYER+1
#define FEAT 128
#define BATCH 128
#define NN (BATCH * NQ * NLAY)   // 130560
#define NE 524288
#define NPAIR (BATCH * NQ * NQ)  // 51200
#define NB (NN / 256)            // 510
#define VOCAB 1021

typedef _Float16 half8 __attribute__((ext_vector_type(8)));
typedef float floatx4 __attribute__((ext_vector_type(4)));

__device__ __forceinline__ float lrelu(float v) { return v >= 0.f ? v : 0.01f * v; }

// ---------------- CSR build ----------------
__global__ void k_count(const int* __restrict__ dst, int* __restrict__ cnt) {
    int e = blockIdx.x * 256 + threadIdx.x;
    atomicAdd(&cnt[dst[e]], 1);
}

// offsets via block-scan + global cursor; also dinv, meta, S0 seed, idmap.
__global__ void k_offsets(const int* __restrict__ cnt, const int* __restrict__ x,
                          int* __restrict__ offs, float* __restrict__ dinv,
                          int4* __restrict__ meta, int* __restrict__ cursor,
                          int* __restrict__ flag1, int* __restrict__ idmap) {
    __shared__ int sm[256];
    __shared__ int sbase;
    int t = threadIdx.x, g = blockIdx.x * 256 + t;
    int v = cnt[g];
    sm[t] = v;
    __syncthreads();
    for (int s = 1; s < 256; s <<= 1) {
        int add = (t >= s) ? sm[t - s] : 0;
        __syncthreads();
        sm[t] += add;
        __syncthreads();
    }
    if (t == 255) sbase = atomicAdd(cursor, sm[255]);
    __syncthreads();
    int off = sbase + sm[t] - v;
    float di = rsqrtf((float)(v + 1));  // +1 self loop
    offs[g] = off;
    dinv[g] = di;
    meta[g] = make_int4(off, v, __float_as_int(di), x[g]);
    if (g % (NQ * NLAY) < NQ) flag1[g] = 1;      // S0 seed
    if (g < 1024) idmap[g] = min(g, VOCAB - 1);
}

// fill packed edges {src, norm_bits} and token edges {x[src], norm_bits};
// norm = dinv[src]*dinv[dst]. Also mark flag1[src] for S0 dsts.
__global__ void k_fill(const int* __restrict__ src, const int* __restrict__ dst,
                       const int* __restrict__ offs, int* __restrict__ fill,
                       const float* __restrict__ dinv, const int* __restrict__ x,
                       int2* __restrict__ csre, int2* __restrict__ csre0,
                       int* __restrict__ flag1) {
    int e = blockIdx.x * 256 + threadIdx.x;
    int d = dst[e];
    int s = src[e];
    int pos = offs[d] + atomicAdd(&fill[d], 1);
    int wb = __float_as_int(dinv[s] * dinv[d]);
    csre[pos] = make_int2(s, wb);
    csre0[pos] = make_int2(x[s], wb);
    if (d % (NQ * NLAY) < NQ) flag1[s] = 1;      // src feeds an S0 node
}

// generic cone pass: emit listO from flagI (cursor-packed dense prefix) and, if flagO,
// mark flagO = flagI-members ∪ their in-neighbors
__global__ void k_s1pass(const int* __restrict__ flagI, const int4* __restrict__ meta,
                         const int2* __restrict__ csre, int* __restrict__ cur,
                         int* __restrict__ listO, int* __restrict__ flagO) {
    __shared__ int sm[256];
    __shared__ int sbase;
    int t = threadIdx.x, g = blockIdx.x * 256 + t;
    int v = flagI[g];
    sm[t] = v;
    __syncthreads();
    for (int s = 1; s < 256; s <<= 1) {
        int add = (t >= s) ? sm[t - s] : 0;
        __syncthreads();
        sm[t] += add;
        __syncthreads();
    }
    if (t == 255) sbase = atomicAdd(cur, sm[255]);
    __syncthreads();
    if (v) {
        listO[sbase + sm[t] - 1] = g;
        if (flagO) {
            flagO[g] = 1;
            int4 m = meta[g];
            for (int e = 0; e < m.y; e++) flagO[csre[m.x + e].x] = 1;   // benign races
        }
    }
}

// emit list from flag (cursor-packed)
__global__ void k_emit2(const int* __restrict__ flag, int* __restrict__ cur,
                        int* __restrict__ list) {
    __shared__ int sm[256];
    __shared__ int sbase;
    int t = threadIdx.x, g = blockIdx.x * 256 + t;
    int v = flag[g];
    sm[t] = v;
    __syncthreads();
    for (int s = 1; s < 256; s <<= 1) {
        int add = (t >= s) ? sm[t - s] : 0;
        __syncthreads();
        sm[t] += add;
        __syncthreads();
    }
    if (t == 255) sbase = atomicAdd(cur, sm[255]);
    __syncthreads();
    if (v) list[sbase + sm[t] - 1] = g;
}

// ---------------- weight transpose + fp16 hi/lo split, PACKED MFMA-fragment layout -------
#define OFF_GCN 0                 // 5 x K=128 N=128
#define OFF_P0  81920             // combined mw0: K=128 N=512
#define OFF_M1  147456            // mw1: K=256 N=128
#define OFF_M2  180224            // mw2: K=128 N=128
#define OFF_M3  196608            // mw3: K=128 N=64
#define OFF_M4  204800            // mw4: K=64  N=64
#define TS_TOTAL 208896

__global__ void k_tsplit_all(const float* __restrict__ gw, const float* __restrict__ mw0,
                             const float* __restrict__ mw1, const float* __restrict__ mw2,
                             const float* __restrict__ mw3, const float* __restrict__ mw4,
                             _Float16* __restrict__ hi, _Float16* __restrict__ lo) {
    int idx = blockIdx.x * 256 + threadIdx.x;
    const float* src;
    int K, N, rel;
    bool p0 = false;
    if (idx < OFF_P0) {
        int L = (idx - OFF_GCN) >> 14; rel = (idx - OFF_GCN) & 16383;
        src = gw + L * 16384; K = 128; N = 128;
    } else if (idx < OFF_M1) {
        rel = idx - OFF_P0; src = mw0; K = 128; N = 512; p0 = true;
    } else if (idx < OFF_M2) {
        rel = idx - OFF_M1;  src = mw1; K = 256; N = 128;
    } else if (idx < OFF_M3) {
        rel = idx - OFF_M2;  src = mw2; K = 128; N = 128;
    } else if (idx < OFF_M4) {
        rel = idx - OFF_M3;  src = mw3; K = 128; N = 64;
    } else {
        rel = idx - OFF_M4;  src = mw4; K = 64;  N = 64;
    }
    int kblks = K >> 5;
    int j = rel & 7;
    int lane = (rel >> 3) & 63;
    int t2 = rel >> 9;
    int kblk = t2 % kblks;
    int ntile = t2 / kblks;
    int col = ntile * 16 + (lane & 15);
    int k = kblk * 32 + ((lane >> 4) << 3) + j;
    float f;
    if (p0) {
        f = (col < 256) ? src[k * 256 + col] : src[(k + 128) * 256 + (col - 256)];
    } else {
        f = src[k * N + col];
    }
    _Float16 h = (_Float16)f;
    hi[idx] = h;
    lo[idx] = (_Float16)(f - (float)h);
}

// ---------------- split-fp16 MFMA GEMM ----------------
template <int NT_N, bool LEAKY, bool BIAS, bool P0SPLIT, bool FUSEA, bool GATHA, bool LISTM>
__launch_bounds__(256, 2)
__global__ void hgemm(const float* __restrict__ A,
                      const float* __restrict__ FA, const float* __restrict__ FB,
                      const _Float16* __restrict__ Bh, const _Float16* __restrict__ Bl,
                      const float* __restrict__ bias,
                      float* __restrict__ C, float* __restrict__ C2,
                      int N, int K, const int* __restrict__ gmap,
                      const int* __restrict__ listm) {
    if (LISTM) {
        if ((unsigned)listm[blockIdx.x * 128] >= (unsigned)NN) return;  // all-sentinel block
    }
    const int KB = K >> 5;
    const int lane = threadIdx.x & 63;
    const int wid = threadIdx.x >> 6;
    const int lm = lane & 15, lq = lane >> 4;
    const int m0 = blockIdx.x * 128 + wid * 32;
    const int n0t = blockIdx.y * NT_N;

    const float* arow[2];
    const float* brow[2];
#pragma unroll
    for (int mt = 0; mt < 2; mt++) {
        int row = m0 + mt * 16 + lm;
        if (FUSEA) {
            int b = row / (NQ * NQ);
            int rr = row - b * (NQ * NQ);
            int i = rr / NQ;
            int j = rr - i * NQ;
            arow[mt] = FA + (size_t)(b * NQ + i) * 256;
            brow[mt] = FB + (size_t)(b * NQ + j) * 256;
        } else if (GATHA) {
            arow[mt] = A + (size_t)gmap[row] * K;
        } else if (LISTM) {
            int lr = listm[row];
            lr = ((unsigned)lr < (unsigned)NN) ? lr : 0;
            arow[mt] = A + (size_t)lr * K;
        } else {
            arow[mt] = A + (size_t)row * K;
        }
    }

    floatx4 acc[2][NT_N];
#pragma unroll
    for (int mt = 0; mt < 2; mt++)
#pragma unroll
        for (int nt = 0; nt < NT_N; nt++) acc[mt][nt] = (floatx4)0.f;

    for (int kb = 0; kb < KB; kb++) {
        const int k0 = kb * 32 + lq * 8;
        half8 ahi[2], alo[2];
#pragma unroll
        for (int mt = 0; mt < 2; mt++) {
            floatx4 av0, av1;
            if (FUSEA) {
                floatx4 fa0 = *(const floatx4*)(arow[mt] + k0);
                floatx4 fa1 = *(const floatx4*)(arow[mt] + k0 + 4);
                floatx4 fb0 = *(const floatx4*)(brow[mt] + k0);
                floatx4 fb1 = *(const floatx4*)(brow[mt] + k0 + 4);
#pragma unroll
                for (int q = 0; q < 4; q++) {
                    av0[q] = lrelu(fa0[q] + fb0[q]);
                    av1[q] = lrelu(fa1[q] + fb1[q]);
                }
            } else {
                av0 = *(const floatx4*)(arow[mt] + k0);
                av1 = *(const floatx4*)(arow[mt] + k0 + 4);
            }
#pragma unroll
            for (int q = 0; q < 4; q++) {
                _Float16 h0 = (_Float16)av0[q];
                ahi[mt][q] = h0;
                alo[mt][q] = (_Float16)(av0[q] - (float)h0);
                _Float16 h1 = (_Float16)av1[q];
                ahi[mt][4 + q] = h1;
                alo[mt][4 + q] = (_Float16)(av1[q] - (float)h1);
            }
        }
#pragma unroll
        for (int nt = 0; nt < NT_N; nt++) {
            size_t boff = (((size_t)(n0t + nt) * KB + kb) * 64 + lane) * 8;
            half8 bhi = *(const half8*)(Bh + boff);
            half8 blo = *(const half8*)(Bl + boff);
#pragma unroll
            for (int mt = 0; mt < 2; mt++) {
                acc[mt][nt] = __builtin_amdgcn_mfma_f32_16x16x32_f16(ahi[mt], bhi, acc[mt][nt], 0, 0, 0);
                acc[mt][nt] = __builtin_amdgcn_mfma_f32_16x16x32_f16(ahi[mt], blo, acc[mt][nt], 0, 0, 0);
                acc[mt][nt] = __builtin_amdgcn_mfma_f32_16x16x32_f16(alo[mt], bhi, acc[mt][nt], 0, 0, 0);
            }
        }
    }

    // store-row mapping (C/D layout: col=lane&15, row=(lane>>4)*4+reg)
    int strow[2][4];
    bool svalid[2][4];
#pragma unroll
    for (int mt = 0; mt < 2; mt++)
#pragma unroll
        for (int r = 0; r < 4; r++) {
            int mlog = m0 + mt * 16 + lq * 4 + r;
            if (LISTM) {
                int sr = listm[mlog];
                svalid[mt][r] = (unsigned)sr < (unsigned)NN;
                strow[mt][r] = svalid[mt][r] ? sr : 0;
            } else {
                svalid[mt][r] = true;
                strow[mt][r] = mlog;
            }
        }

#pragma unroll
    for (int nt = 0; nt < NT_N; nt++) {
        int col = (n0t + nt) * 16 + lm;
        float bv = (BIAS || P0SPLIT) ? bias[col < 256 ? col : 0] : 0.f;
#pragma unroll
        for (int mt = 0; mt < 2; mt++) {
#pragma unroll
            for (int r = 0; r < 4; r++) {
                if (!svalid[mt][r]) continue;
                int row = strow[mt][r];
                float val = acc[mt][nt][r];
                if (P0SPLIT) {
                    if (col < 256) C[(size_t)row * 256 + col] = val + bv;
                    else C2[(size_t)row * 256 + col - 256] = val;
                } else {
                    if (BIAS) val += bv;
                    if (LEAKY) val = lrelu(val);
                    C[(size_t)row * N + col] = val;
                }
            }
        }
    }
}

// ---------------- layer-0 aggregation from the L2-resident token table ----------------
__global__ void k_agg0(const float* __restrict__ embW, const float* __restrict__ emb,
                       float* __restrict__ h,
                       const int4* __restrict__ meta, const int2* __restrict__ csre0,
                       const float* __restrict__ bias) {
    int tid = threadIdx.x;
    int sl = tid & 31;
    int p = blockIdx.x * 8 + (tid >> 5);
    int n0 = p * 2, n1 = n0 + 1;
    int4 m0 = meta[n0], m1 = meta[n1];
    float di0 = __int_as_float(m0.z), di1 = __int_as_float(m1.z);
    int off0 = m0.x, deg0 = m0.y;
    int off1 = m1.x, deg1 = m1.y;
    float4 v0 = ((const float4*)(embW + (size_t)m0.w * FEAT))[sl];
    float4 v1 = ((const float4*)(embW + (size_t)m1.w * FEAT))[sl];
    float4 ho0 = ((const float4*)(emb + (size_t)m0.w * FEAT))[sl];
    float4 ho1 = ((const float4*)(emb + (size_t)m1.w * FEAT))[sl];
    float s20 = di0 * di0, s21 = di1 * di1;
    float a0x = v0.x * s20, a0y = v0.y * s20, a0z = v0.z * s20, a0w = v0.w * s20;
    float a1x = v1.x * s21, a1y = v1.y * s21, a1z = v1.z * s21, a1w = v1.w * s21;
    int d0c = max(deg0 - 1, 0), d1c = max(deg1 - 1, 0);
    int dm = max(deg0, deg1);
    for (int e = 0; e < dm; e += 4) {
        int2 e00 = csre0[off0 + min(e,     d0c)];
        int2 e01 = csre0[off0 + min(e + 1, d0c)];
        int2 e02 = csre0[off0 + min(e + 2, d0c)];
        int2 e03 = csre0[off0 + min(e + 3, d0c)];
        int2 e10 = csre0[off1 + min(e,     d1c)];
        int2 e11 = csre0[off1 + min(e + 1, d1c)];
        int2 e12 = csre0[off1 + min(e + 2, d1c)];
        int2 e13 = csre0[off1 + min(e + 3, d1c)];
        float4 u00 = ((const float4*)(embW + (size_t)e00.x * FEAT))[sl];
        float4 u01 = ((const float4*)(embW + (size_t)e01.x * FEAT))[sl];
        float4 u02 = ((const float4*)(embW + (size_t)e02.x * FEAT))[sl];
        float4 u03 = ((const float4*)(embW + (size_t)e03.x * FEAT))[sl];
        float4 u10 = ((const float4*)(embW + (size_t)e10.x * FEAT))[sl];
        float4 u11 = ((const float4*)(embW + (size_t)e11.x * FEAT))[sl];
        float4 u12 = ((const float4*)(embW + (size_t)e12.x * FEAT))[sl];
        float4 u13 = ((const float4*)(embW + (size_t)e13.x * FEAT))[sl];
        float w00 = (e     < deg0) ? __int_as_float(e00.y) : 0.f;
        float w01 = (e + 1 < deg0) ? __int_as_float(e01.y) : 0.f;
        float w02 = (e + 2 < deg0) ? __int_as_float(e02.y) : 0.f;
        float w03 = (e + 3 < deg0) ? __int_as_float(e03.y) : 0.f;
        float w10 = (e     < deg1) ? __int_as_float(e10.y) : 0.f;
        float w11 = (e + 1 < deg1) ? __int_as_float(e11.y) : 0.f;
        float w12 = (e + 2 < deg1) ? __int_as_float(e12.y) : 0.f;
        float w13 = (e + 3 < deg1) ? __int_as_float(e13.y) : 0.f;
        a0x += u00.x * w00 + u01.x * w01 + u02.x * w02 + u03.x * w03;
        a0y += u00.y * w00 + u01.y * w01 + u02.y * w02 + u03.y * w03;
        a0z += u00.z * w00 + u01.z * w01 + u02.z * w02 + u03.z * w03;
        a0w += u00.w * w00 + u01.w * w01 + u02.w * w02 + u03.w * w03;
        a1x += u10.x * w10 + u11.x * w11 + u12.x * w12 + u13.x * w13;
        a1y += u10.y * w10 + u11.y * w11 + u12.y * w12 + u13.y * w13;
        a1z += u10.z * w10 + u11.z * w11 + u12.z * w12 + u13.z * w13;
        a1w += u10.w * w10 + u11.w * w11 + u12.w * w12 + u13.w * w13;
    }
    float4 bv = ((const float4*)bias)[sl];
    float4 r0, r1;
    r0.x = lrelu(a0x + bv.x) + ho0.x;
    r0.y = lrelu(a0y + bv.y) + ho0.y;
    r0.z = lrelu(a0z + bv.z) + ho0.z;
    r0.w = lrelu(a0w + bv.w) + ho0.w;
    r1.x = lrelu(a1x + bv.x) + ho1.x;
    r1.y = lrelu(a1y + bv.y) + ho1.y;
    r1.z = lrelu(a1z + bv.z) + ho1.z;
    r1.w = lrelu(a1w + bv.w) + ho1.w;
    ((float4*)(h + (size_t)n0 * FEAT))[sl] = r0;
    ((float4*)(h + (size_t)n1 * FEAT))[sl] = r1;
}

// ---------------- GCN aggregation + bias + leaky + residual, h IN PLACE ----------------
// Sentinel-padded dense-prefix list; block early exit; clamp; store suppress.
__global__ void k_agg(const float* __restrict__ hw, float* __restrict__ h,
                      const int4* __restrict__ meta, const int2* __restrict__ csre,
                      const int* __restrict__ list,
                      const float* __restrict__ bias) {
    if ((unsigned)list[blockIdx.x * 16] >= (unsigned)NN) return;  // all-sentinel block
    int tid = threadIdx.x;
    int sl = tid & 31;
    int p = blockIdx.x * 8 + (tid >> 5);
    int n0 = list[p * 2];
    int n1 = list[p * 2 + 1];
    bool val0 = (unsigned)n0 < (unsigned)NN;
    bool val1 = (unsigned)n1 < (unsigned)NN;
    n0 = val0 ? n0 : 0;
    n1 = val1 ? n1 : 0;
    int4 m0 = meta[n0], m1 = meta[n1];
    float di0 = __int_as_float(m0.z), di1 = __int_as_float(m1.z);
    int off0 = m0.x, deg0 = val0 ? m0.y : 0;
    int off1 = m1.x, deg1 = val1 ? m1.y : 0;
    float4 v0 = ((const float4*)(hw + (size_t)n0 * FEAT))[sl];
    float4 v1 = ((const float4*)(hw + (size_t)n1 * FEAT))[sl];
    float4 ho0 = ((const float4*)(h + (size_t)n0 * FEAT))[sl];
    float4 ho1 = ((const float4*)(h + (size_t)n1 * FEAT))[sl];
    float s20 = di0 * di0, s21 = di1 * di1;
    float a0x = v0.x * s20, a0y = v0.y * s20, a0z = v0.z * s20, a0w = v0.w * s20;
    float a1x = v1.x * s21, a1y = v1.y * s21, a1z = v1.z * s21, a1w = v1.w * s21;
    int d0c = max(deg0 - 1, 0), d1c = max(deg1 - 1, 0);
    int dm = max(deg0, deg1);
    for (int e = 0; e < dm; e += 6) {
        int2 e00 = csre[off0 + min(e,     d0c)];
        int2 e01 = csre[off0 + min(e + 1, d0c)];
        int2 e02 = csre[off0 + min(e + 2, d0c)];
        int2 e03 = csre[off0 + min(e + 3, d0c)];
        int2 e04 = csre[off0 + min(e + 4, d0c)];
        int2 e05 = csre[off0 + min(e + 5, d0c)];
        int2 e10 = csre[off1 + min(e,     d1c)];
        int2 e11 = csre[off1 + min(e + 1, d1c)];
        int2 e12 = csre[off1 + min(e + 2, d1c)];
        int2 e13 = csre[off1 + min(e + 3, d1c)];
        int2 e14 = csre[off1 + min(e + 4, d1c)];
        int2 e15 = csre[off1 + min(e + 5, d1c)];
        float4 u00 = ((const float4*)(hw + (size_t)e00.x * FEAT))[sl];
        float4 u01 = ((const float4*)(hw + (size_t)e01.x * FEAT))[sl];
        float4 u02 = ((const float4*)(hw + (size_t)e02.x * FEAT))[sl];
        float4 u03 = ((const float4*)(hw + (size_t)e03.x * FEAT))[sl];
        float4 u04 = ((const float4*)(hw + (size_t)e04.x * FEAT))[sl];
        float4 u05 = ((const float4*)(hw + (size_t)e05.x * FEAT))[sl];
        float4 u10 = ((const float4*)(hw + (size_t)e10.x * FEAT))[sl];
        float4 u11 = ((const float4*)(hw + (size_t)e11.x * FEAT))[sl];
        float4 u12 = ((const float4*)(hw + (size_t)e12.x * FEAT))[sl];
        float4 u13 = ((const float4*)(hw + (size_t)e13.x * FEAT))[sl];
        float4 u14 = ((const float4*)(hw + (size_t)e14.x * FEAT))[sl];
        float4 u15 = ((const float4*)(hw + (size_t)e15.x * FEAT))[sl];
        float w00 = (e     < deg0) ? __int_as_float(e00.y) : 0.f;
        float w01 = (e + 1 < deg0) ? __int_as_float(e01.y) : 0.f;
        float w02 = (e + 2 < deg0) ? __int_as_float(e02.y) : 0.f;
        float w03 = (e + 3 < deg0) ? __int_as_float(e03.y) : 0.f;
        float w04 = (e + 4 < deg0) ? __int_as_float(e04.y) : 0.f;
        float w05 = (e + 5 < deg0) ? __int_as_float(e05.y) : 0.f;
        float w10 = (e     < deg1) ? __int_as_float(e10.y) : 0.f;
        float w11 = (e + 1 < deg1) ? __int_as_float(e11.y) : 0.f;
        float w12 = (e + 2 < deg1) ? __int_as_float(e12.y) : 0.f;
        float w13 = (e + 3 < deg1) ? __int_as_float(e13.y) : 0.f;
        float w14 = (e + 4 < deg1) ? __int_as_float(e14.y) : 0.f;
        float w15 = (e + 5 < deg1) ? __int_as_float(e15.y) : 0.f;
        a0x += u00.x * w00 + u01.x * w01 + u02.x * w02 + u03.x * w03 + u04.x * w04 + u05.x * w05;
        a0y += u00.y * w00 + u01.y * w01 + u02.y * w02 + u03.y * w03 + u04.y * w04 + u05.y * w05;
        a0z += u00.z * w00 + u01.z * w01 + u02.z * w02 + u03.z * w03 + u04.z * w04 + u05.z * w05;
        a0w += u00.w * w00 + u01.w * w01 + u02.w * w02 + u03.w * w03 + u04.w * w04 + u05.w * w05;
        a1x += u10.x * w10 + u11.x * w11 + u12.x * w12 + u13.x * w13 + u14.x * w14 + u15.x * w15;
        a1y += u10.y * w10 + u11.y * w11 + u12.y * w12 + u13.y * w13 + u14.y * w14 + u15.y * w15;
        a1z += u10.z * w10 + u11.z * w11 + u12.z * w12 + u13.z * w13 + u14.z * w14 + u15.z * w15;
        a1w += u10.w * w10 + u11.w * w11 + u12.w * w12 + u13.w * w13 + u14.w * w14 + u15.w * w15;
    }
    float4 bv = ((const float4*)bias)[sl];
    float4 r0, r1;
    r0.x = lrelu(a0x + bv.x) + ho0.x;
    r0.y = lrelu(a0y + bv.y) + ho0.y;
    r0.z = lrelu(a0z + bv.z) + ho0.z;
    r0.w = lrelu(a0w + bv.w) + ho0.w;
    r1.x = lrelu(a1x + bv.x) + ho1.x;
    r1.y = lrelu(a1y + bv.y) + ho1.y;
    r1.z = lrelu(a1z + bv.z) + ho1.z;
    r1.w = lrelu(a1w + bv.w) + ho1.w;
    if (val0) ((float4*)(h + (size_t)n0 * FEAT))[sl] = r0;
    if (val1) ((float4*)(h + (size_t)n1 * FEAT))[sl] = r1;
}

// ---------------- selective final agg (layer 4): S0 rows only -> hq, no leaky ----------------
__global__ void k_aggq(const float* __restrict__ hw, const float* __restrict__ h,
                       const int4* __restrict__ meta, const int2* __restrict__ csre,
                       const float* __restrict__ gbias, float* __restrict__ hq) {
    int tid = threadIdx.x;
    int sl = tid & 31;
    int q = blockIdx.x * 8 + (tid >> 5);   // 0..2559
    int b = q / NQ, i = q - b * NQ;
    int node = b * (NQ * NLAY) + i;
    int4 m = meta[node];
    float di = __int_as_float(m.z);
    int off = m.x, deg = m.y;
    float s2 = di * di;
    float4 v = ((const float4*)(hw + (size_t)node * FEAT))[sl];
    float ax = v.x * s2, ay = v.y * s2, az = v.z * s2, aw = v.w * s2;
    int dc = max(deg - 1, 0);
    for (int e = 0; e < deg; e += 4) {
        int2 e0 = csre[off + min(e,     dc)];
        int2 e1 = csre[off + min(e + 1, dc)];
        int2 e2 = csre[off + min(e + 2, dc)];
        int2 e3 = csre[off + min(e + 3, dc)];
        float4 u0 = ((const float4*)(hw + (size_t)e0.x * FEAT))[sl];
        float4 u1 = ((const float4*)(hw + (size_t)e1.x * FEAT))[sl];
        float4 u2 = ((const float4*)(hw + (size_t)e2.x * FEAT))[sl];
        float4 u3 = ((const float4*)(hw + (size_t)e3.x * FEAT))[sl];
        float w0 = (e     < deg) ? __int_as_float(e0.y) : 0.f;
        float w1 = (e + 1 < deg) ? __int_as_float(e1.y) : 0.f;
        float w2 = (e + 2 < deg) ? __int_as_float(e2.y) : 0.f;
        float w3 = (e + 3 < deg) ? __int_as_float(e3.y) : 0.f;
        ax += u0.x * w0 + u1.x * w1 + u2.x * w2 + u3.x * w3;
        ay += u0.y * w0 + u1.y * w1 + u2.y * w2 + u3.y * w3;
        az += u0.z * w0 + u1.z * w1 + u2.z * w2 + u3.z * w3;
        aw += u0.w * w0 + u1.w * w1 + u2.w * w2 + u3.w * w3;
    }
    float4 bv = ((const float4*)gbias)[sl];
    float4 ho = ((const float4*)(h + (size_t)node * FEAT))[sl];
    ((float4*)(hq + (size_t)q * FEAT))[sl] =
        make_float4(ax + bv.x + ho.x, ay + bv.y + ho.y, az + bv.z + ho.z, aw + bv.w + ho.w);
}

// ---------------- last layer + symmetrize, one block per batch ----------------
__global__ void k_lastsym(const float* __restrict__ X4, const float* __restrict__ mw5,
                          const float* __restrict__ mb5, float* __restrict__ out) {
    __shared__ float w[64];
    __shared__ float sm[NQ * NQ];
    int t = threadIdx.x;
    if (t < 64) w[t] = mw5[t];
    __syncthreads();
    int b = blockIdx.x;
    for (int p = t; p < NQ * NQ; p += 256) {
        const float4* row = (const float4*)(X4 + (size_t)(b * NQ * NQ + p) * 64);
        float s = 0.f;
#pragma unroll
        for (int k4 = 0; k4 < 16; k4++) {
            float4 v = row[k4];
            s += v.x * w[k4 * 4] + v.y * w[k4 * 4 + 1] + v.z * w[k4 * 4 + 2] + v.w * w[k4 * 4 + 3];
        }
        sm[p] = s + mb5[0];
    }
    __syncthreads();
    for (int r = t; r < NQ * NQ; r += 256) {
        int i = r / NQ, j = r % NQ;
        out[(size_t)b * NQ * NQ + r] = 0.5f * (sm[r] + sm[j * NQ + i]);
    }
}

extern "C" void kernel_launch(void* const* d_in, const int* in_sizes, int n_in,
                              void* d_out, int out_size, void* d_ws, size_t ws_size,
                              hipStream_t stream) {
    const int* x = (const int*)d_in[0];
    const int* ei = (const int*)d_in[1];
    const int* e_src = ei;
    const int* e_dst = ei + NE;
    const float* emb = (const float*)d_in[2];
    const float* gw = (const float*)d_in[3];   // [5,128,128]
    const float* gb = (const float*)d_in[4];   // [5,128]
    const float* mw0 = (const float*)d_in[5];
    const float* mb0 = (const float*)d_in[6];
    const float* mw1 = (const float*)d_in[7];
    const float* mb1 = (const float*)d_in[8];
    const float* mw2 = (const float*)d_in[9];
    const float* mb2 = (const float*)d_in[10];
    const float* mw3 = (const float*)d_in[11];
    const float* mb3 = (const float*)d_in[12];
    const float* mw4 = (const float*)d_in[13];
    const float* mb4 = (const float*)d_in[14];
    const float* mw5 = (const float*)d_in[15];
    const float* mb5 = (const float*)d_in[16];
    float* out = (float*)d_out;

    float* wsf = (float*)d_ws;
    size_t o = 0;
    const size_t HSZ = (size_t)NN * FEAT;             // 16,711,680
    float* h  = wsf + o; o += HSZ;    // single in-place h buffer
    float* hw = wsf + o; o += HSZ;
    // zero-memset region: cnt, fill, flag1, flag2, flag3, cursors (contiguous)
    int* cnt   = (int*)(wsf + o); o += NN;
    int* fill  = (int*)(wsf + o); o += NN;
    int* flag1 = (int*)(wsf + o); o += NN;
    int* flag2 = (int*)(wsf + o); o += NN;
    int* flag3 = (int*)(wsf + o); o += NN;
    int* curs  = (int*)(wsf + o); o += 16;   // [0]=offs [1]=list1 [2]=list2 [3]=list3
    // 0xFF-memset region: list1, list2, list3 (contiguous, sentinel -1)
    int* list1 = (int*)(wsf + o); o += NN;
    int* list2 = (int*)(wsf + o); o += NN;
    int* list3 = (int*)(wsf + o); o += NN;
    int* offs = (int*)(wsf + o); o += NN;
    float* dinv = wsf + o; o += NN;
    int4* meta = (int4*)(wsf + o); o += 4 * (size_t)NN;
    int2* csre  = (int2*)(wsf + o); o += 2 * (size_t)(NE + 8);  // +8 slop for deg-0 clamp
    int2* csre0 = (int2*)(wsf + o); o += 2 * (size_t)(NE + 8);  // token edges
    int* idmap = (int*)(wsf + o); o += 1024;
    float* embW = wsf + o; o += (size_t)1024 * FEAT;          // emb@W0 table
    float* hq = wsf + o; o += (size_t)BATCH * NQ * FEAT;      // 327,680
    float* Abuf = wsf + o; o += (size_t)BATCH * NQ * 256;     // 655,360
    float* Bbuf = wsf + o; o += (size_t)BATCH * NQ * 256;     // 655,360
    _Float16* bt_hi = (_Float16*)(wsf + o); o += (TS_TOTAL + 2) / 2;
    _Float16* bt_lo = (_Float16*)(wsf + o); o += (TS_TOTAL + 2) / 2;
    // pair-phase aliases (hw, h dead after aggq)
    float* X1 = hw;                         // 51200*128
    float* X2 = hw + (size_t)NPAIR * 128;   // 51200*128
    float* X3 = h;                          // 51200*64
    float* X4 = h + (size_t)NPAIR * 64;     // 51200*64

    // --- weight transpose+split+pack ---
    k_tsplit_all<<<TS_TOTAL / 256, 256, 0, stream>>>(gw, mw0, mw1, mw2, mw3, mw4, bt_hi, bt_lo);

    // --- CSR build + cone lists S1/S2/S3 ---
    hipMemsetAsync(cnt, 0, (5 * NN + 16) * sizeof(int), stream); // cnt+fill+flags+cursors
    hipMemsetAsync(list1, 0xFF, 3 * NN * sizeof(int), stream);   // list sentinels (-1)
    hipMemsetAsync(csre + NE, 0, 8 * sizeof(int2), stream);      // slop
    hipMemsetAsync(csre0 + NE, 0, 8 * sizeof(int2), stream);     // slop
    k_count<<<NE / 256, 256, 0, stream>>>(e_dst, cnt);
    k_offsets<<<NB, 256, 0, stream>>>(cnt, x, offs, dinv, meta, curs + 0, flag1, idmap);
    k_fill<<<NE / 256, 256, 0, stream>>>(e_src, e_dst, offs, fill, dinv, x, csre, csre0, flag1);
    k_s1pass<<<NB, 256, 0, stream>>>(flag1, meta, csre, curs + 1, list1, flag2);  // S1 + mark S2
    k_s1pass<<<NB, 256, 0, stream>>>(flag2, meta, csre, curs + 2, list2, flag3);  // S2 + mark S3
    k_emit2<<<NB, 256, 0, stream>>>(flag3, curs + 3, list3);                      // S3

    // --- layer 0 via token table: embW = emb@W0 (1021 rows, clamped id map) ---
    hgemm<8, false, false, false, false, true, false><<<dim3(8, 1), 256, 0, stream>>>(
        emb, nullptr, nullptr, bt_hi + OFF_GCN, bt_lo + OFF_GCN,
        nullptr, embW, nullptr, FEAT, FEAT, idmap, nullptr);
    k_agg0<<<NN / 16, 256, 0, stream>>>(embW, emb, h, meta, csre0, gb + 0 * FEAT);

    // --- layer 1: full gemm + agg@S3 ---
    hgemm<8, false, false, false, false, false, false><<<dim3(NN / 128, 1), 256, 0, stream>>>(
        h, nullptr, nullptr, bt_hi + OFF_GCN + 1 * 16384, bt_lo + OFF_GCN + 1 * 16384,
        nullptr, hw, nullptr, FEAT, FEAT, nullptr, nullptr);
    k_agg<<<NN / 16, 256, 0, stream>>>(hw, h, meta, csre, list3, gb + 1 * FEAT);

    // --- layer 2: gemm@S3 + agg@S2 ---
    hgemm<8, false, false, false, false, false, true><<<dim3(NN / 128, 1), 256, 0, stream>>>(
        h, nullptr, nullptr, bt_hi + OFF_GCN + 2 * 16384, bt_lo + OFF_GCN + 2 * 16384,
        nullptr, hw, nullptr, FEAT, FEAT, nullptr, list3);
    k_agg<<<NN / 16, 256, 0, stream>>>(hw, h, meta, csre, list2, gb + 2 * FEAT);

    // --- layer 3: gemm@S2 + agg@S1 ---
    hgemm<8, false, false, false, false, false, true><<<dim3(NN / 128, 1), 256, 0, stream>>>(
        h, nullptr, nullptr, bt_hi + OFF_GCN + 3 * 16384, bt_lo + OFF_GCN + 3 * 16384,
        nullptr, hw, nullptr, FEAT, FEAT, nullptr, list2);
    k_agg<<<NN / 16, 256, 0, stream>>>(hw, h, meta, csre, list1, gb + 3 * FEAT);

    // --- layer 4: gemm@S1 + selective agg@S0 -> hq ---
    hgemm<8, false, false, false, false, false, true><<<dim3(NN / 128, 1), 256, 0, stream>>>(
        h, nullptr, nullptr, bt_hi + OFF_GCN + 4 * 16384, bt_lo + OFF_GCN + 4 * 16384,
        nullptr, hw, nullptr, FEAT, FEAT, nullptr, list1);
    k_aggq<<<(BATCH * NQ) / 8, 256, 0, stream>>>(hw, h, meta, csre,
                                                 gb + 4 * (size_t)FEAT, hq);

    // --- pair MLP ---
    hgemm<8, false, false, true, false, false, false><<<dim3(20, 4), 256, 0, stream>>>(
        hq, nullptr, nullptr, bt_hi + OFF_P0, bt_lo + OFF_P0, mb0, Abuf, Bbuf, 512, 128,
        nullptr, nullptr);
    hgemm<8, true, true, false, true, false, false><<<dim3(NPAIR / 128, 1), 256, 0, stream>>>(
        nullptr, Abuf, Bbuf, bt_hi + OFF_M1, bt_lo + OFF_M1, mb1, X1, nullptr, 128, 256,
        nullptr, nullptr);
    hgemm<8, true, true, false, false, false, false><<<dim3(NPAIR / 128, 1), 256, 0, stream>>>(
        X1, nullptr, nullptr, bt_hi + OFF_M2, bt_lo + OFF_M2, mb2, X2, nullptr, 128, 128,
        nullptr, nullptr);
    hgemm<4, true, true, false, false, false, false><<<dim3(NPAIR / 128, 1), 256, 0, stream>>>(
        X2, nullptr, nullptr, bt_hi + OFF_M3, bt_lo + OFF_M3, mb3, X3, nullptr, 64, 128,
        nullptr, nullptr);
    hgemm<4, true, true, false, false, false, false><<<dim3(NPAIR / 128, 1), 256, 0, stream>>>(
        X3, nullptr, nullptr, bt_hi + OFF_M4, bt_lo + OFF_M4, mb4, X4, nullptr, 64, 64,
        nullptr, nullptr);
    k_lastsym<<<BATCH, 256, 0, stream>>>(X4, mw5, mb5, out);
}